// Round 1
// baseline (332.970 us; speedup 1.0000x reference)
//
#include <hip/hip_runtime.h>
#include <hip/hip_bf16.h>

#define DIM_K 4096
#define DIM_N 4096
#define M_TOK 8192

#define BM 128
#define BN 128
#define BK 32

typedef __attribute__((ext_vector_type(8))) short bf16x8;
typedef __attribute__((ext_vector_type(4))) float f32x4;

typedef const __attribute__((address_space(1))) unsigned int gu32;
typedef __attribute__((address_space(3))) unsigned int lu32;

__device__ __forceinline__ unsigned short f2bf(float f) {
  unsigned int u = __float_as_uint(f);
  u += 0x7FFFu + ((u >> 16) & 1u);   // round-to-nearest-even
  return (unsigned short)(u >> 16);
}

__device__ __forceinline__ void gload_lds16(const void* g, void* l) {
  __builtin_amdgcn_global_load_lds((gu32*)g, (lu32*)l, 16, 0, 0);
}

// ---------------- pre-pass 1: x fp32 [M][K] -> bf16 [M][K] ----------------
__global__ void cvt_x_kernel(const float* __restrict__ x,
                             unsigned short* __restrict__ xb, int n4) {
  int idx = blockIdx.x * blockDim.x + threadIdx.x;
  int stride = gridDim.x * blockDim.x;
  for (int i = idx; i < n4; i += stride) {
    float4 v = reinterpret_cast<const float4*>(x)[i];
    ushort4 o;
    o.x = f2bf(v.x); o.y = f2bf(v.y); o.z = f2bf(v.z); o.w = f2bf(v.w);
    reinterpret_cast<ushort4*>(xb)[i] = o;
  }
}

// ---------- pre-pass 2: W fp32 [K][N] -> Wt bf16 [N][K] (transpose) --------
__global__ void cvt_wt_kernel(const float* __restrict__ W,
                              unsigned short* __restrict__ Wt) {
  __shared__ unsigned short tile[32][33];  // +1 pad breaks bank conflicts
  const int k0 = blockIdx.x * 32;
  const int n0 = blockIdx.y * 32;
  const int tx = threadIdx.x;  // 0..31
  const int ty = threadIdx.y;  // 0..7
#pragma unroll
  for (int j = 0; j < 4; ++j) {
    int k = k0 + ty + 8 * j;
    tile[ty + 8 * j][tx] = f2bf(W[(size_t)k * DIM_N + n0 + tx]);
  }
  __syncthreads();
#pragma unroll
  for (int j = 0; j < 4; ++j) {
    int n = n0 + ty + 8 * j;
    Wt[(size_t)n * DIM_K + k0 + tx] = tile[tx][ty + 8 * j];
  }
}

// ---------------- GEMM: C[M][N] = A[M][K] * Wt[N][K]^T (bf16 MFMA) ---------
// Staircase: n-tile determines kend (1024 / 2048 / 4096).
__global__ __launch_bounds__(256) void gemm_kernel(
    const unsigned short* __restrict__ A,   // [M][K] bf16
    const unsigned short* __restrict__ Bt,  // [N][K] bf16
    float* __restrict__ C) {
  __shared__ unsigned short As[BM * BK];  // 8 KB, row-major [128][32]
  __shared__ unsigned short Bs[BN * BK];  // 8 KB

  const int tid = threadIdx.x;
  const int lane = tid & 63;
  const int wid = tid >> 6;     // 0..3
  const int wrow = wid >> 1;    // 0..1
  const int wcol = wid & 1;     // 0..1

  const int m0 = blockIdx.x * BM;
  const int n0 = blockIdx.y * BN;
  const int kend = (n0 < 1024) ? 1024 : (n0 < 2048 ? 2048 : 4096);

  // global_load_lds staging map: wave w, chunk c covers LDS bytes
  // [w*2048 + c*1024, +1024); lane i -> 16B at row (w*32+c*16+i/4), col 8*(i&3)
  const int r0 = wid * 32 + (lane >> 2);
  const int r1 = r0 + 16;
  const int kk = 8 * (lane & 3);

  // fragment read indices (16x16x32 bf16 A/B layout: row/col = lane&15,
  // k = (lane>>4)*8 + j)
  const int arow = wrow * 64 + (lane & 15);
  const int brow = wcol * 64 + (lane & 15);
  const int ksl = (lane >> 4) * 8;

  f32x4 acc[4][4];
#pragma unroll
  for (int i = 0; i < 4; ++i)
#pragma unroll
    for (int j = 0; j < 4; ++j)
      acc[i][j] = (f32x4){0.f, 0.f, 0.f, 0.f};

  const unsigned short* Abase = A + (size_t)m0 * DIM_K;
  const unsigned short* Bbase = Bt + (size_t)n0 * DIM_K;

  for (int k0 = 0; k0 < kend; k0 += BK) {
    __syncthreads();  // previous compute done before overwriting LDS
    gload_lds16(Abase + (size_t)r0 * DIM_K + k0 + kk, (void*)(As + wid * 1024));
    gload_lds16(Abase + (size_t)r1 * DIM_K + k0 + kk, (void*)(As + wid * 1024 + 512));
    gload_lds16(Bbase + (size_t)r0 * DIM_K + k0 + kk, (void*)(Bs + wid * 1024));
    gload_lds16(Bbase + (size_t)r1 * DIM_K + k0 + kk, (void*)(Bs + wid * 1024 + 512));
    __syncthreads();  // staging visible (compiler drains vmcnt before barrier)

    bf16x8 a[4], b[4];
#pragma unroll
    for (int mi = 0; mi < 4; ++mi)
      a[mi] = *reinterpret_cast<const bf16x8*>(As + (arow + mi * 16) * BK + ksl);
#pragma unroll
    for (int ni = 0; ni < 4; ++ni)
      b[ni] = *reinterpret_cast<const bf16x8*>(Bs + (brow + ni * 16) * BK + ksl);

#pragma unroll
    for (int mi = 0; mi < 4; ++mi)
#pragma unroll
      for (int ni = 0; ni < 4; ++ni)
        acc[mi][ni] = __builtin_amdgcn_mfma_f32_16x16x32_bf16(
            a[mi], b[ni], acc[mi][ni], 0, 0, 0);
  }

  // C/D layout (measured m89/m91): col = lane&15, row = (lane>>4)*4 + reg
  const int crow = m0 + wrow * 64 + (lane >> 4) * 4;
  const int ccol = n0 + wcol * 64 + (lane & 15);
#pragma unroll
  for (int mi = 0; mi < 4; ++mi)
#pragma unroll
    for (int ni = 0; ni < 4; ++ni) {
      float* Cp = C + (size_t)(crow + mi * 16) * DIM_N + ccol + ni * 16;
#pragma unroll
      for (int r = 0; r < 4; ++r) Cp[(size_t)r * DIM_N] = acc[mi][ni][r];
    }
}

extern "C" void kernel_launch(void* const* d_in, const int* in_sizes, int n_in,
                              void* d_out, int out_size, void* d_ws,
                              size_t ws_size, hipStream_t stream) {
  const float* x = (const float*)d_in[0];
  const float* W = (const float*)d_in[1];
  float* out = (float*)d_out;

  // workspace layout: [0, 64MB) x_bf16 ; [64MB, 96MB) Wt_bf16
  unsigned short* xb = (unsigned short*)d_ws;
  unsigned short* wt = xb + (size_t)M_TOK * DIM_K;

  cvt_x_kernel<<<2048, 256, 0, stream>>>(x, xb, M_TOK * DIM_K / 4);
  cvt_wt_kernel<<<dim3(DIM_K / 32, DIM_N / 32), dim3(32, 8), 0, stream>>>(W, wt);
  gemm_kernel<<<dim3(M_TOK / BM, DIM_N / BN), 256, 0, stream>>>(xb, wt, out);
}

// Round 2
// 238.696 us; speedup vs baseline: 1.3950x; 1.3950x over previous
//
#include <hip/hip_runtime.h>
#include <hip/hip_bf16.h>

#define DIM_K 4096
#define DIM_N 4096
#define M_TOK 8192

typedef __attribute__((ext_vector_type(8))) short bf16x8;
typedef __attribute__((ext_vector_type(4))) float f32x4;

typedef const __attribute__((address_space(1))) unsigned int gu32;
typedef __attribute__((address_space(3))) unsigned int lu32;

__device__ __forceinline__ unsigned short f2bf(float f) {
  unsigned int u = __float_as_uint(f);
  u += 0x7FFFu + ((u >> 16) & 1u);   // round-to-nearest-even
  return (unsigned short)(u >> 16);
}

__device__ __forceinline__ void gload_lds16(const void* g, void* l) {
  __builtin_amdgcn_global_load_lds((gu32*)g, (lu32*)l, 16, 0, 0);
}

// ---------------- pre-pass 1: x fp32 [M][K] -> bf16 [M][K] ----------------
__global__ void cvt_x_kernel(const float* __restrict__ x,
                             unsigned short* __restrict__ xb, int n4) {
  int idx = blockIdx.x * blockDim.x + threadIdx.x;
  int stride = gridDim.x * blockDim.x;
  for (int i = idx; i < n4; i += stride) {
    float4 v = reinterpret_cast<const float4*>(x)[i];
    ushort4 o;
    o.x = f2bf(v.x); o.y = f2bf(v.y); o.z = f2bf(v.z); o.w = f2bf(v.w);
    reinterpret_cast<ushort4*>(xb)[i] = o;
  }
}

// ---------- pre-pass 2: W fp32 [K][N] -> Wt bf16 [N][K] (transpose) --------
__global__ void cvt_wt_kernel(const float* __restrict__ W,
                              unsigned short* __restrict__ Wt) {
  __shared__ unsigned short tile[32][33];
  const int k0 = blockIdx.x * 32;
  const int n0 = blockIdx.y * 32;
  const int tx = threadIdx.x;  // 0..31
  const int ty = threadIdx.y;  // 0..7
#pragma unroll
  for (int j = 0; j < 4; ++j) {
    int k = k0 + ty + 8 * j;
    tile[ty + 8 * j][tx] = f2bf(W[(size_t)k * DIM_N + n0 + tx]);
  }
  __syncthreads();
#pragma unroll
  for (int j = 0; j < 4; ++j) {
    int n = n0 + ty + 8 * j;
    Wt[(size_t)n * DIM_K + k0 + tx] = tile[tx][ty + 8 * j];
  }
}

// ---------------------------------------------------------------------------
// 256x256-tile GEMM, C[M][N] = A[M][K] * Bt[N][K]^T, bf16 MFMA 16x16x32.
// Phase-interleaved schedule (T3+T4), counted vmcnt (never 0 in loop),
// 4-deep circular LDS buffer of BK=32 K-tiles, XOR-swizzled LDS (T2),
// setprio around MFMA clusters (T5). Staircase: kend per n-tile.
//
// LDS per K-tile: A [256 rows][32 k] bf16 (16KB) + B [256 n][32 k] (16KB).
// Swizzle (element space): slot_k = k ^ (((row>>1)&3)<<3) — spreads the 16
// rows of a quarter-wave's ds_read_b128 over all 8 16B chunk-slots (2-way).
// Staged via linear LDS dest + inverse-swizzled per-lane GLOBAL source.
// ---------------------------------------------------------------------------
__global__ __launch_bounds__(512, 2) void gemm_kernel(
    const unsigned short* __restrict__ A,   // [M][K] bf16
    const unsigned short* __restrict__ Bt,  // [N][K] bf16
    float* __restrict__ C) {
  __shared__ unsigned short lds[65536];  // 128 KB = 4 bufs x (A 8K + B 8K shorts)

  const int tid = threadIdx.x;
  const int lane = tid & 63;
  const int w = tid >> 6;   // 0..7
  const int wr = w >> 2;    // 0..1 : M half (128 rows)
  const int wc = w & 3;     // 0..3 : N quarter (64 cols)

  const int bid = blockIdx.x;
  const int bx = bid & 31;           // m-tile
  const int by = 15 - (bid >> 5);    // n-tile; heavy (kend=4096) first
  const int m0 = bx * 256;
  const int n0 = by * 256;
  const int kend = (n0 < 1024) ? 1024 : (n0 < 2048 ? 2048 : 4096);
  const int nk = kend >> 5;          // K-tiles of 32 (32 / 64 / 128)

  const unsigned short* Abase = A + (size_t)m0 * DIM_K;
  const unsigned short* Bbase = Bt + (size_t)n0 * DIM_K;

  // --- staging geometry: chunk i in {0,1}; LDS byte L = i*8192 + w*1024 + lane*16
  //     r = L>>6 (tile row), chunk-slot kc=(L>>4)&3, source k = (kc ^ ((r>>1)&3))*8
  int srcoff[2];
#pragma unroll
  for (int i = 0; i < 2; ++i) {
    int L = i * 8192 + w * 1024 + lane * 16;
    int r = L >> 6;
    int kc = (L >> 4) & 3;
    int ks = (kc ^ ((r >> 1) & 3)) << 3;
    srcoff[i] = r * DIM_K + ks;
  }
  const int dstoffA0 = w * 512;          // shorts, wave-uniform (HW adds lane*16B)
  const int dstoffA1 = 4096 + w * 512;

  // --- fragment read geometry (16x16x32: row/col = lane&15, k = (lane>>4)*8+j)
  const int l15 = lane & 15;
  const int kb = (lane >> 4) << 3;
  const int rA = wr * 128 + l15;
  const int rB = wc * 64 + l15;
  const int koffA = kb ^ (((rA >> 1) & 3) << 3);
  const int koffB = kb ^ (((rB >> 1) & 3) << 3);

#define AFRAG(bufc, mi) \
  (*reinterpret_cast<const bf16x8*>(&lds[(bufc)*16384 + (rA + (mi)*16)*32 + koffA]))
#define BFRAG(bufc, ni) \
  (*reinterpret_cast<const bf16x8*>(&lds[(bufc)*16384 + 8192 + (rB + (ni)*16)*32 + koffB]))

#define STAGE_A(kt, bufc)                                                     \
  do {                                                                        \
    gload_lds16(Abase + (size_t)(kt) * 32 + srcoff[0], &lds[(bufc)*16384 + dstoffA0]); \
    gload_lds16(Abase + (size_t)(kt) * 32 + srcoff[1], &lds[(bufc)*16384 + dstoffA1]); \
  } while (0)
#define STAGE_B(kt, bufc)                                                     \
  do {                                                                        \
    gload_lds16(Bbase + (size_t)(kt) * 32 + srcoff[0], &lds[(bufc)*16384 + 8192 + dstoffA0]); \
    gload_lds16(Bbase + (size_t)(kt) * 32 + srcoff[1], &lds[(bufc)*16384 + 8192 + dstoffA1]); \
  } while (0)

  f32x4 acc[8][4];
#pragma unroll
  for (int i = 0; i < 8; ++i)
#pragma unroll
    for (int j = 0; j < 4; ++j) acc[i][j] = (f32x4){0.f, 0.f, 0.f, 0.f};

  // --- prologue: stage K-tiles 0,1,2 ; wait tile 0 (leave 8 loads in flight)
  STAGE_A(0, 0); STAGE_B(0, 0);
  STAGE_A(1, 1); STAGE_B(1, 1);
  STAGE_A(2, 2); STAGE_B(2, 2);
  asm volatile("s_waitcnt vmcnt(8)" ::: "memory");
  __builtin_amdgcn_s_barrier();

  // --- main loop: 2 phases per K-tile, buffer k&3, stage lead 3
  for (int kk = 0; kk < nk; kk += 4) {
#pragma unroll
    for (int u = 0; u < 4; ++u) {
      const int k = kk + u;
      const int buf = u;              // (kk+u)&3 with kk%4==0
      const int sb = (u + 3) & 3;
      const int kt = (k + 3 < nk) ? (k + 3) : (nk - 1);

      // ---- phase a: C rows 0-63 of wave ----
      bf16x8 afr[4], bfr[4];
#pragma unroll
      for (int mi = 0; mi < 4; ++mi) afr[mi] = AFRAG(buf, mi);
#pragma unroll
      for (int ni = 0; ni < 4; ++ni) bfr[ni] = BFRAG(buf, ni);
      STAGE_A(kt, sb);
      __builtin_amdgcn_s_barrier();
      __builtin_amdgcn_s_setprio(1);
#pragma unroll
      for (int mi = 0; mi < 4; ++mi)
#pragma unroll
        for (int ni = 0; ni < 4; ++ni)
          acc[mi][ni] = __builtin_amdgcn_mfma_f32_16x16x32_bf16(
              afr[mi], bfr[ni], acc[mi][ni], 0, 0, 0);
      __builtin_amdgcn_s_setprio(0);
      asm volatile("s_waitcnt lgkmcnt(0)" ::: "memory");  // reads done pre-barrier
      __builtin_amdgcn_s_barrier();

      // ---- phase b: C rows 64-127 of wave ----
      bf16x8 afr2[4];
#pragma unroll
      for (int mi = 0; mi < 4; ++mi) afr2[mi] = AFRAG(buf, mi + 4);
      STAGE_B(kt, sb);
      asm volatile("s_waitcnt vmcnt(8)" ::: "memory");    // tile k+1 resident
      __builtin_amdgcn_s_barrier();
      __builtin_amdgcn_s_setprio(1);
#pragma unroll
      for (int mi = 0; mi < 4; ++mi)
#pragma unroll
        for (int ni = 0; ni < 4; ++ni)
          acc[mi + 4][ni] = __builtin_amdgcn_mfma_f32_16x16x32_bf16(
              afr2[mi], bfr[ni], acc[mi + 4][ni], 0, 0, 0);
      __builtin_amdgcn_s_setprio(0);
      asm volatile("s_waitcnt lgkmcnt(0)" ::: "memory");
      __builtin_amdgcn_s_barrier();
    }
  }

  // --- epilogue: C/D layout col=lane&15, row=(lane>>4)*4+reg
  const int crow0 = m0 + wr * 128 + (lane >> 4) * 4;
  const int ccol0 = n0 + wc * 64 + l15;
#pragma unroll
  for (int mi = 0; mi < 8; ++mi)
#pragma unroll
    for (int ni = 0; ni < 4; ++ni) {
      float* Cp = C + (size_t)(crow0 + mi * 16) * DIM_N + ccol0 + ni * 16;
#pragma unroll
      for (int r2 = 0; r2 < 4; ++r2) Cp[(size_t)r2 * DIM_N] = acc[mi][ni][r2];
    }
#undef AFRAG
#undef BFRAG
#undef STAGE_A
#undef STAGE_B
}

extern "C" void kernel_launch(void* const* d_in, const int* in_sizes, int n_in,
                              void* d_out, int out_size, void* d_ws,
                              size_t ws_size, hipStream_t stream) {
  const float* x = (const float*)d_in[0];
  const float* W = (const float*)d_in[1];
  float* out = (float*)d_out;

  unsigned short* xb = (unsigned short*)d_ws;                  // 64 MB
  unsigned short* wt = xb + (size_t)M_TOK * DIM_K;             // 32 MB

  cvt_x_kernel<<<2048, 256, 0, stream>>>(x, xb, M_TOK * DIM_K / 4);
  cvt_wt_kernel<<<dim3(DIM_K / 32, DIM_N / 32), dim3(32, 8), 0, stream>>>(W, wt);
  gemm_kernel<<<512, 512, 0, stream>>>(xb, wt, out);
}